// Round 1
// baseline (776.393 us; speedup 1.0000x reference)
//
#include <hip/hip_runtime.h>
#include <math.h>

#define TPAD 68   // LDS pitch: multiple of 4 (aligned float4), 68%32=4 -> <=2-way banks

// ---------------------------------------------------------------------------
// Kernel AB: fc1 (768->64) + 8x 64x64 chain + residual + exact GELU
// Block: 256 threads, 64 tokens. Micro-tile 4x4 per thread.
// LDS layout [k][m] so float4 reads along m are aligned.
// ---------------------------------------------------------------------------
__global__ __launch_bounds__(256) void k_fc1_chain(
    const float* __restrict__ x, const float* __restrict__ fc1_w,
    const float* __restrict__ fc1_b, const float* __restrict__ conv_w,
    const float* __restrict__ conv_b, float* __restrict__ xs)
{
    __shared__ float lds[3 * 64 * TPAD];
    float* bufA = lds;                 // fc1 A-tile / act ping  [ch][tok]
    float* bufB = lds + 64 * TPAD;     // fc1 B-tile / act pong
    float* bufW = lds + 2 * 64 * TPAD; // chain weights [c][o]

    const int tid = threadIdx.x;
    const int tx = tid & 15;
    const int ty = tid >> 4;
    const int t0 = blockIdx.x * 64;
    const int scol = tx * 4;

    float acc[4][4];
#pragma unroll
    for (int i = 0; i < 4; ++i)
#pragma unroll
        for (int j = 0; j < 4; ++j) acc[i][j] = 0.f;

    for (int k0 = 0; k0 < 768; k0 += 64) {
#pragma unroll
        for (int i = 0; i < 4; ++i) {
            const int row = ty + i * 16;   // token idx / out idx (0..63)
            const float4 xv = *(const float4*)(x + (size_t)(t0 + row) * 768 + k0 + scol);
            bufA[(scol + 0) * TPAD + row] = xv.x;
            bufA[(scol + 1) * TPAD + row] = xv.y;
            bufA[(scol + 2) * TPAD + row] = xv.z;
            bufA[(scol + 3) * TPAD + row] = xv.w;
            const float4 wv = *(const float4*)(fc1_w + (size_t)row * 768 + k0 + scol);
            bufB[(scol + 0) * TPAD + row] = wv.x;
            bufB[(scol + 1) * TPAD + row] = wv.y;
            bufB[(scol + 2) * TPAD + row] = wv.z;
            bufB[(scol + 3) * TPAD + row] = wv.w;
        }
        __syncthreads();
#pragma unroll 16
        for (int k = 0; k < 64; ++k) {
            const float4 a4 = *(const float4*)(bufA + k * TPAD + ty * 4);
            const float4 b4 = *(const float4*)(bufB + k * TPAD + tx * 4);
            const float a[4] = {a4.x, a4.y, a4.z, a4.w};
            const float b[4] = {b4.x, b4.y, b4.z, b4.w};
#pragma unroll
            for (int i = 0; i < 4; ++i)
#pragma unroll
                for (int j = 0; j < 4; ++j) acc[i][j] = fmaf(a[i], b[j], acc[i][j]);
        }
        __syncthreads();
    }

    // fc1 bias -> write activation tile into bufA as [ch][tok]
#pragma unroll
    for (int i = 0; i < 4; ++i)
#pragma unroll
        for (int j = 0; j < 4; ++j)
            bufA[(tx * 4 + j) * TPAD + (ty * 4 + i)] = acc[i][j] + fc1_b[tx * 4 + j];

    float* cur = bufA;
    float* nxt = bufB;
    float res[4][4];

    for (int l = 0; l < 8; ++l) {
        // stage conv_w[l] (64x64, [o][c] in global) into bufW as [c][o]
#pragma unroll
        for (int i = 0; i < 4; ++i) {
            const int row = ty + i * 16;  // o
            const float4 wv = *(const float4*)(conv_w + l * 4096 + row * 64 + scol);
            bufW[(scol + 0) * TPAD + row] = wv.x;
            bufW[(scol + 1) * TPAD + row] = wv.y;
            bufW[(scol + 2) * TPAD + row] = wv.z;
            bufW[(scol + 3) * TPAD + row] = wv.w;
        }
        __syncthreads();  // B1: bufW staged + prev act writes visible

#pragma unroll
        for (int i = 0; i < 4; ++i)
#pragma unroll
            for (int j = 0; j < 4; ++j) acc[i][j] = 0.f;
#pragma unroll 16
        for (int k = 0; k < 64; ++k) {
            const float4 a4 = *(const float4*)(cur + k * TPAD + ty * 4);
            const float4 b4 = *(const float4*)(bufW + k * TPAD + tx * 4);
            const float a[4] = {a4.x, a4.y, a4.z, a4.w};
            const float b[4] = {b4.x, b4.y, b4.z, b4.w};
#pragma unroll
            for (int i = 0; i < 4; ++i)
#pragma unroll
                for (int j = 0; j < 4; ++j) acc[i][j] = fmaf(a[i], b[j], acc[i][j]);
        }
#pragma unroll
        for (int i = 0; i < 4; ++i)
#pragma unroll
            for (int j = 0; j < 4; ++j) acc[i][j] += conv_b[l * 64 + tx * 4 + j];

        if (l == 5) {
#pragma unroll
            for (int i = 0; i < 4; ++i)
#pragma unroll
                for (int j = 0; j < 4; ++j) res[i][j] = acc[i][j];
        }
        if (l < 7) {
            __syncthreads();  // B2: all reads of cur/bufW done
#pragma unroll
            for (int i = 0; i < 4; ++i)
#pragma unroll
                for (int j = 0; j < 4; ++j)
                    nxt[(tx * 4 + j) * TPAD + (ty * 4 + i)] = acc[i][j];
            float* t = cur; cur = nxt; nxt = t;
        }
    }

    // epilogue: residual (h after layer 5) + exact GELU, store token-major
#pragma unroll
    for (int i = 0; i < 4; ++i) {
        float4 g4;
        float v;
        v = acc[i][0] + res[i][0]; g4.x = 0.5f * v * (1.f + erff(v * 0.70710678118654752f));
        v = acc[i][1] + res[i][1]; g4.y = 0.5f * v * (1.f + erff(v * 0.70710678118654752f));
        v = acc[i][2] + res[i][2]; g4.z = 0.5f * v * (1.f + erff(v * 0.70710678118654752f));
        v = acc[i][3] + res[i][3]; g4.w = 0.5f * v * (1.f + erff(v * 0.70710678118654752f));
        *(float4*)(xs + (size_t)(t0 + ty * 4 + i) * 64 + tx * 4) = g4;
    }
}

// ---------------------------------------------------------------------------
// Kernel C: qkv. Reads xs at flat index c*65536 + p (the free "reshape"
// reinterpretation), writes qkv planar [n][p]. One thread per pixel.
// ---------------------------------------------------------------------------
__global__ __launch_bounds__(256) void k_qkv(
    const float* __restrict__ xs, const float* __restrict__ qkv_w,
    const float* __restrict__ qkv_b, float* __restrict__ qkv)
{
    __shared__ float wq[48 * 64];
    __shared__ float qb[48];
    const int tid = threadIdx.x;
    for (int i = tid; i < 48 * 64; i += 256) wq[i] = qkv_w[i];
    if (tid < 48) qb[tid] = qkv_b[tid];
    __syncthreads();

    const int p = blockIdx.x * 256 + tid;
    float acc[48];
#pragma unroll
    for (int n = 0; n < 48; ++n) acc[n] = qb[n];

    for (int c = 0; c < 64; c += 4) {
        const float xv0 = xs[(c + 0) * 65536 + p];
        const float xv1 = xs[(c + 1) * 65536 + p];
        const float xv2 = xs[(c + 2) * 65536 + p];
        const float xv3 = xs[(c + 3) * 65536 + p];
#pragma unroll
        for (int n = 0; n < 48; ++n) {
            const float4 w4 = *(const float4*)(wq + n * 64 + c);
            acc[n] += xv0 * w4.x + xv1 * w4.y + xv2 * w4.z + xv3 * w4.w;
        }
    }
#pragma unroll
    for (int n = 0; n < 48; ++n) qkv[n * 65536 + p] = acc[n];
}

// ---------------------------------------------------------------------------
// Kernel D: shift-conv + dw-conv + rpb + softmax(9) + weighted V + proj.
// One thread per pixel; per-thread o16 parked in LDS to avoid dynamic
// register-array indexing across the nh loop.
// ---------------------------------------------------------------------------
__global__ __launch_bounds__(256) void k_attn(
    const float* __restrict__ qkv, const float* __restrict__ dep1_w,
    const float* __restrict__ dep_b, const float* __restrict__ dep1_b,
    const float* __restrict__ rpb, const float* __restrict__ proj_w,
    const float* __restrict__ proj_b, float* __restrict__ obuf)
{
    __shared__ float s_d1w[162];
    __shared__ float s_db[18];
    __shared__ float s_d1b[18];
    __shared__ float s_rpb[72];
    __shared__ float s_pw[1024];
    __shared__ float s_pb[64];
    __shared__ float s_o[256 * 17];   // per-thread 16 vals, pitch 17

    const int tid = threadIdx.x;
    for (int i = tid; i < 162; i += 256) s_d1w[i] = dep1_w[i];
    if (tid < 18) { s_db[tid] = dep_b[tid]; s_d1b[tid] = dep1_b[tid]; }
    if (tid < 72) s_rpb[tid] = rpb[tid];
    for (int i = tid; i < 1024; i += 256) s_pw[i] = proj_w[i];
    if (tid < 64) s_pb[tid] = proj_b[tid];
    __syncthreads();

    const int p = blockIdx.x * 256 + tid;
    const int h = p >> 11;
    const int w = p & 2047;

    int np[9];
    float vmask[9];
#pragma unroll
    for (int t = 0; t < 9; ++t) {
        const int dh = t / 3 - 1, dw = t % 3 - 1;
        const int hh = h + dh, ww = w + dw;
        const bool ok = ((unsigned)hh < 32u) && ((unsigned)ww < 2048u);
        np[t] = ok ? (hh * 2048 + ww) : p;
        vmask[t] = ok ? 1.f : 0.f;
    }

    float* my = s_o + tid * 17;

    for (int nh = 0; nh < 8; ++nh) {
        const float* base = qkv + nh * 6 * 65536;
        const float q0 = base[p];
        const float q1 = base[65536 + p];

        float kn[2][9];
#pragma unroll
        for (int c = 0; c < 2; ++c)
#pragma unroll
            for (int t = 0; t < 9; ++t)
                kn[c][t] = base[(2 + c) * 65536 + np[t]] * vmask[t];

        float lg[9];
#pragma unroll
        for (int i = 0; i < 9; ++i) {
            float s = 0.f;
#pragma unroll
            for (int c = 0; c < 2; ++c) {
                const int o = c * 9 + i;
                float conv = 0.f;
#pragma unroll
                for (int t = 0; t < 9; ++t) conv = fmaf(kn[c][t], s_d1w[o * 9 + t], conv);
                const float k6 = kn[c][i] + conv + s_db[o] + s_d1b[o] + s_rpb[nh * 9 + i];
                s = fmaf((c == 0 ? q0 : q1), k6, s);
            }
            lg[i] = s * 0.35355339059327373f;  // (C_HID/NH)^-0.5 = 8^-0.5
        }
        float m = lg[0];
#pragma unroll
        for (int i = 1; i < 9; ++i) m = fmaxf(m, lg[i]);
        float sum = 0.f;
#pragma unroll
        for (int i = 0; i < 9; ++i) { lg[i] = expf(lg[i] - m); sum += lg[i]; }
        const float inv = 1.f / sum;

        float vn[2][9];
#pragma unroll
        for (int c = 0; c < 2; ++c)
#pragma unroll
            for (int t = 0; t < 9; ++t)
                vn[c][t] = base[(4 + c) * 65536 + np[t]] * vmask[t];

#pragma unroll
        for (int c = 0; c < 2; ++c) {
            float ov = 0.f;
#pragma unroll
            for (int i = 0; i < 9; ++i) {
                const int o = c * 9 + i;
                float conv = 0.f;
#pragma unroll
                for (int t = 0; t < 9; ++t) conv = fmaf(vn[c][t], s_d1w[o * 9 + t], conv);
                const float v6 = vn[c][i] + conv + s_db[o] + s_d1b[o];
                ov = fmaf(lg[i], v6, ov);
            }
            my[nh * 2 + c] = ov * inv;
        }
    }

    // proj 16 -> 64, write channel-planar (free final reshape)
    for (int d = 0; d < 64; ++d) {
        float s = s_pb[d];
#pragma unroll
        for (int j = 0; j < 16; ++j) s = fmaf(my[j], s_pw[d * 16 + j], s);
        obuf[d * 65536 + p] = s;
    }
}

// ---------------------------------------------------------------------------
// Kernel E: fc2 (64->768) + bias + residual x. TM=64, TN=128, K=64.
// obuf read token-major (t*64+k) -- the free reinterpretation again.
// ---------------------------------------------------------------------------
#define EPB 132  // Bs pitch (multiple of 4)

__global__ __launch_bounds__(256) void k_fc2(
    const float* __restrict__ ot, const float* __restrict__ fc2_w,
    const float* __restrict__ fc2_b, const float* __restrict__ x,
    float* __restrict__ out)
{
    __shared__ float As[64 * TPAD];  // [k][t] 64x64
    __shared__ float Bs[64 * EPB];   // [k][n] 64x128

    const int tid = threadIdx.x;
    const int tx = tid & 15;
    const int ty = tid >> 4;
    const int t0 = blockIdx.x * 64;
    const int n0 = blockIdx.y * 128;
    const int scol = tx * 4;

#pragma unroll
    for (int i = 0; i < 4; ++i) {
        const int r = ty + i * 16;  // token
        const float4 v = *(const float4*)(ot + (size_t)(t0 + r) * 64 + scol);
        As[(scol + 0) * TPAD + r] = v.x;
        As[(scol + 1) * TPAD + r] = v.y;
        As[(scol + 2) * TPAD + r] = v.z;
        As[(scol + 3) * TPAD + r] = v.w;
    }
#pragma unroll
    for (int i = 0; i < 8; ++i) {
        const int r = ty + i * 16;  // n (0..127)
        const float4 v = *(const float4*)(fc2_w + (size_t)(n0 + r) * 64 + scol);
        Bs[(scol + 0) * EPB + r] = v.x;
        Bs[(scol + 1) * EPB + r] = v.y;
        Bs[(scol + 2) * EPB + r] = v.z;
        Bs[(scol + 3) * EPB + r] = v.w;
    }
    __syncthreads();

    float acc[4][8];
#pragma unroll
    for (int i = 0; i < 4; ++i)
#pragma unroll
        for (int j = 0; j < 8; ++j) acc[i][j] = 0.f;

#pragma unroll 8
    for (int k = 0; k < 64; ++k) {
        const float4 a4 = *(const float4*)(As + k * TPAD + ty * 4);
        const float4 b40 = *(const float4*)(Bs + k * EPB + tx * 8);
        const float4 b41 = *(const float4*)(Bs + k * EPB + tx * 8 + 4);
        const float a[4] = {a4.x, a4.y, a4.z, a4.w};
        const float b[8] = {b40.x, b40.y, b40.z, b40.w, b41.x, b41.y, b41.z, b41.w};
#pragma unroll
        for (int i = 0; i < 4; ++i)
#pragma unroll
            for (int j = 0; j < 8; ++j) acc[i][j] = fmaf(a[i], b[j], acc[i][j]);
    }

    float bb[8];
#pragma unroll
    for (int j = 0; j < 8; ++j) bb[j] = fc2_b[n0 + tx * 8 + j];

#pragma unroll
    for (int i = 0; i < 4; ++i) {
        const size_t off = (size_t)(t0 + ty * 4 + i) * 768 + n0 + tx * 8;
        const float4 x0 = *(const float4*)(x + off);
        const float4 x1 = *(const float4*)(x + off + 4);
        float4 r0, r1;
        r0.x = acc[i][0] + bb[0] + x0.x;
        r0.y = acc[i][1] + bb[1] + x0.y;
        r0.z = acc[i][2] + bb[2] + x0.z;
        r0.w = acc[i][3] + bb[3] + x0.w;
        r1.x = acc[i][4] + bb[4] + x1.x;
        r1.y = acc[i][5] + bb[5] + x1.y;
        r1.z = acc[i][6] + bb[6] + x1.z;
        r1.w = acc[i][7] + bb[7] + x1.w;
        *(float4*)(out + off) = r0;
        *(float4*)(out + off + 4) = r1;
    }
}

// ---------------------------------------------------------------------------
extern "C" void kernel_launch(void* const* d_in, const int* in_sizes, int n_in,
                              void* d_out, int out_size, void* d_ws, size_t ws_size,
                              hipStream_t stream) {
    const float* x      = (const float*)d_in[0];
    const float* fc1_w  = (const float*)d_in[1];
    const float* fc1_b  = (const float*)d_in[2];
    const float* conv_w = (const float*)d_in[3];
    const float* conv_b = (const float*)d_in[4];
    const float* qkv_w  = (const float*)d_in[5];
    const float* qkv_b  = (const float*)d_in[6];
    const float* dep1_w = (const float*)d_in[7];
    const float* dep_b  = (const float*)d_in[8];
    const float* dep1_b = (const float*)d_in[9];
    const float* rpb    = (const float*)d_in[10];
    const float* proj_w = (const float*)d_in[11];
    const float* proj_b = (const float*)d_in[12];
    const float* fc2_w  = (const float*)d_in[13];
    const float* fc2_b  = (const float*)d_in[14];

    float* ws   = (float*)d_ws;
    float* xs   = ws;                 // 64*65536       = 4,194,304 f
    float* qkv  = ws + 4194304;       // 48*65536       = 3,145,728 f
    float* obuf = ws + 7340032;       // 64*65536       = 4,194,304 f
    float* out  = (float*)d_out;

    k_fc1_chain<<<dim3(1024), dim3(256), 0, stream>>>(x, fc1_w, fc1_b, conv_w, conv_b, xs);
    k_qkv<<<dim3(256), dim3(256), 0, stream>>>(xs, qkv_w, qkv_b, qkv);
    k_attn<<<dim3(256), dim3(256), 0, stream>>>(qkv, dep1_w, dep_b, dep1_b, rpb,
                                                proj_w, proj_b, obuf);
    k_fc2<<<dim3(1024, 6), dim3(256), 0, stream>>>(obuf, fc2_w, fc2_b, x, out);
}